// Round 18
// baseline (759.633 us; speedup 1.0000x reference)
//
#include <hip/hip_runtime.h>
#include <hip/hip_fp16.h>
#include <math.h>

#define KG_E  50000
#define KG_R  500
#define E_DIM 300
#define NPAIR 150
#define NP2   75
#define CAP   1024
#define LRELU 0.2f

#define NK    10
#define NT    40
#define XS_LD 328

#define NB_SCAN 49

typedef __attribute__((ext_vector_type(8))) _Float16 f16x8;
typedef __attribute__((ext_vector_type(4))) float f32x4;

__device__ __forceinline__ __half2 u2h2(unsigned u) {
  union { unsigned u; __half2 h; } v; v.u = u; return v.h;
}
__device__ __forceinline__ unsigned h22u(__half2 h) {
  union { unsigned u; __half2 h; } v; v.h = h; return v.u;
}
__device__ __forceinline__ float hlo(unsigned u) { return __low2float(u2h2(u)); }
__device__ __forceinline__ float hhi(unsigned u) { return __high2float(u2h2(u)); }
__device__ __forceinline__ unsigned packh(float lo, float hi) {
  return h22u(__floats2half2_rn(lo, hi));
}

// ---------------- f32 -> fp16 table conversion -----------------------------
__global__ __launch_bounds__(256) void k_toh(
    const float* __restrict__ src, __half* __restrict__ dst, int n4)
{
  int i = blockIdx.x * 256 + threadIdx.x;
  if (i >= n4) return;
  float4 f = ((const float4*)src)[i];
  uint2 o;
  o.x = packh(f.x, f.y);
  o.y = packh(f.z, f.w);
  ((uint2*)dst)[i] = o;
}

// ---------------- compaction: 20 floats/thread, 10k blocks -----------------
#define NCH 10
#define SCAP 1024
#define NF4 1250
__global__ __launch_bounds__(256) void k_compact2(
    const float* __restrict__ r_head, const float* __restrict__ r_tail,
    const float* __restrict__ be_L, const float* __restrict__ be_R,
    int* __restrict__ lidx, float* __restrict__ lsval,
    int* __restrict__ fill, float* __restrict__ rsum)
{
  __shared__ int   ls_e[SCAP];
  __shared__ float ls_v[SCAP];
  __shared__ int   ls_cnt;
  __shared__ float ls_sum;
  __shared__ int   ls_base;
  int m = blockIdx.z;
  int r = blockIdx.y;
  const float* rowp = (m ? r_tail : r_head) + (size_t)r * KG_E;
  const float* be   = m ? be_R : be_L;
  int slot = m * KG_R + r;
  int lane = threadIdx.x & 63;
  if (threadIdx.x == 0) { ls_cnt = 0; ls_sum = 0.f; }
  __syncthreads();

  const int CH = KG_E / NCH;
  int c0 = blockIdx.x * CH;
  const float4* rp4 = (const float4*)(rowp + c0);

  float vals[20];
  #pragma unroll
  for (int t = 0; t < 5; ++t) {
    int fi = t * 256 + threadIdx.x;
    float4 f = (fi < NF4) ? rp4[fi] : make_float4(0.f, 0.f, 0.f, 0.f);
    vals[t*4+0] = f.x; vals[t*4+1] = f.y; vals[t*4+2] = f.z; vals[t*4+3] = f.w;
  }
  float lsum = 0.f;
  int cnt = 0;
  #pragma unroll
  for (int q = 0; q < 20; ++q) {
    lsum += vals[q];
    cnt += (vals[q] != 0.f) ? 1 : 0;
  }
  int pre = cnt;
  #pragma unroll
  for (int off = 1; off < 64; off <<= 1) {
    int u = __shfl_up(pre, off, 64);
    if (lane >= off) pre += u;
  }
  int wave_base = 0;
  if (lane == 63 && pre > 0) wave_base = atomicAdd(&ls_cnt, pre);
  wave_base = __shfl(wave_base, 63, 64);
  if (cnt > 0) {
    int o = wave_base + pre - cnt;
    #pragma unroll
    for (int t = 0; t < 5; ++t) {
      int fi = t * 256 + threadIdx.x;
      #pragma unroll
      for (int q = 0; q < 4; ++q) {
        float v = vals[t*4+q];
        if (v != 0.f) {
          if (o < SCAP) {
            int e = c0 + fi * 4 + q;
            ls_e[o] = e;
            ls_v[o] = v * be[e];
          }
          ++o;
        }
      }
    }
  }
  #pragma unroll
  for (int off = 32; off > 0; off >>= 1) lsum += __shfl_xor(lsum, off, 64);
  if (lane == 0 && lsum != 0.f) atomicAdd(&ls_sum, lsum);
  __syncthreads();

  int total = ls_cnt < SCAP ? ls_cnt : SCAP;
  if (threadIdx.x == 0) {
    ls_base = atomicAdd(&fill[slot], total);
    if (ls_sum != 0.f) atomicAdd(&rsum[slot], ls_sum);
  }
  __syncthreads();
  int gbase = ls_base;
  int*   li = lidx  + (size_t)slot * CAP;
  float* lv = lsval + (size_t)slot * CAP;
  for (int i = threadIdx.x; i < total; i += 256) {
    int pos = gbase + i;
    if (pos < CAP) { li[pos] = ls_e[i]; lv[pos] = ls_v[i]; }
  }
}

__global__ __launch_bounds__(256) void k_rmeta(
    const int* __restrict__ fill, const float* __restrict__ rsum,
    int* __restrict__ cnt, float* __restrict__ inv)
{
  int i = blockIdx.x * 256 + threadIdx.x;
  if (i < 2 * KG_R) {
    int c = fill[i];
    cnt[i] = c > CAP ? CAP : c;
    float s = rsum[i];
    inv[i] = (s == 0.f) ? 0.f : 1.f / s;
  }
}

// ---------------- r-layer ---------------------------------------------------
__global__ __launch_bounds__(192) void k_rlayer(
    const __half* __restrict__ Eb, const int* __restrict__ lidx,
    const float* __restrict__ lsval, const int* __restrict__ cnt,
    const float* __restrict__ inv, const float* __restrict__ atten,
    unsigned* __restrict__ wpk)
{
  int b = blockIdx.x;
  int m = b / KG_R, r = b % KG_R;
  int p = threadIdx.x;
  if (p >= NPAIR) return;
  int slot = m * KG_R + r;
  int n = cnt[slot];
  const int*   li = lidx  + (size_t)slot * CAP;
  const float* lv = lsval + (size_t)slot * CAP;
  float alo = 0.f, ahi = 0.f;
  #pragma unroll 4
  for (int i = 0; i < n; ++i) {
    int e = li[i];
    float s = lv[i];
    unsigned u = ((const unsigned*)(Eb + (size_t)e * E_DIM))[p];
    alo += s * hlo(u);
    ahi += s * hhi(u);
  }
  float iv = inv[slot];
  float vlo = alo * iv; vlo = vlo > 0.f ? vlo : 0.f;
  float vhi = ahi * iv; vhi = vhi > 0.f ? vhi : 0.f;
  vlo *= atten[m * E_DIM + 2 * p];
  vhi *= atten[m * E_DIM + 2 * p + 1];
  wpk[(size_t)slot * NPAIR + p] = packh(vlo, vhi);
}

// ---------------- CSR build -------------------------------------------------
__global__ __launch_bounds__(256) void k_hist(
    const int* __restrict__ rows, int* __restrict__ cnt, int n)
{
  int i = blockIdx.x * 256 + threadIdx.x;
  if (i < n) atomicAdd(&cnt[rows[i]], 1);
}

__global__ __launch_bounds__(256) void k_scan_a(
    const int* __restrict__ c0, const int* __restrict__ c1,
    int* __restrict__ bsum, int n)
{
  const int* c = blockIdx.y ? c1 : c0;
  int base = blockIdx.x * 1024;
  int s = 0;
  #pragma unroll
  for (int k = 0; k < 4; ++k) {
    int i = base + k * 256 + threadIdx.x;
    if (i < n) s += c[i];
  }
  #pragma unroll
  for (int off = 32; off > 0; off >>= 1) s += __shfl_xor(s, off, 64);
  __shared__ int ws[4];
  if ((threadIdx.x & 63) == 0) ws[threadIdx.x >> 6] = s;
  __syncthreads();
  if (threadIdx.x == 0)
    bsum[blockIdx.y * (NB_SCAN + 1) + blockIdx.x] = ws[0] + ws[1] + ws[2] + ws[3];
}

__global__ __launch_bounds__(64) void k_scan_b(int* __restrict__ bsum)
{
  if (threadIdx.x < 2) {
    int* b = bsum + threadIdx.x * (NB_SCAN + 1);
    int acc = 0;
    for (int i = 0; i < NB_SCAN; ++i) { int v = b[i]; b[i] = acc; acc += v; }
    b[NB_SCAN] = acc;
  }
}

__global__ __launch_bounds__(256) void k_scan_c(
    const int* __restrict__ c0, const int* __restrict__ c1,
    const int* __restrict__ bsum,
    int* __restrict__ s0, int* __restrict__ s1, int n)
{
  const int* c = blockIdx.y ? c1 : c0;
  int* sO = blockIdx.y ? s1 : s0;
  if (blockIdx.x == 0 && threadIdx.x == 0)
    sO[n] = bsum[blockIdx.y * (NB_SCAN + 1) + NB_SCAN];
  int boff = bsum[blockIdx.y * (NB_SCAN + 1) + blockIdx.x];
  int i0 = blockIdx.x * 1024 + threadIdx.x * 4;
  int4 v = {0, 0, 0, 0};
  if (i0 < n) v = ((const int4*)c)[i0 >> 2];
  int tsum = v.x + v.y + v.z + v.w;
  int lane = threadIdx.x & 63, wid = threadIdx.x >> 6;
  int inc = tsum;
  #pragma unroll
  for (int off = 1; off < 64; off <<= 1) {
    int u = __shfl_up(inc, off, 64);
    if (lane >= off) inc += u;
  }
  __shared__ int ws[4];
  if (lane == 63) ws[wid] = inc;
  __syncthreads();
  int woff = 0;
  if (wid > 0) woff += ws[0];
  if (wid > 1) woff += ws[1];
  if (wid > 2) woff += ws[2];
  int ex = boff + woff + inc - tsum;
  if (i0 < n) {
    int4 o;
    o.x = ex; o.y = ex + v.x; o.z = o.y + v.y; o.w = o.z + v.z;
    ((int4*)sO)[i0 >> 2] = o;
  }
}

__global__ __launch_bounds__(256) void k_scatter_eer(
    const int* __restrict__ eidx, const int* __restrict__ erel,
    const int* __restrict__ start, int* __restrict__ fill,
    int* __restrict__ scol, int* __restrict__ srel, int neer)
{
  int i = blockIdx.x * 256 + threadIdx.x;
  if (i >= neer) return;
  int row = eidx[i];
  int pos = start[row] + atomicAdd(&fill[row], 1);
  scol[pos] = eidx[neer + i];
  srel[pos] = erel[i];
}

__global__ __launch_bounds__(256) void k_scatter_adj(
    const int* __restrict__ aidx, const float* __restrict__ adata,
    const int* __restrict__ start, int* __restrict__ fill,
    int* __restrict__ scol, float* __restrict__ sval, int ne)
{
  int i = blockIdx.x * 256 + threadIdx.x;
  if (i >= ne) return;
  int row = aidx[i];
  int pos = start[row] + atomicAdd(&fill[row], 1);
  scol[pos] = aidx[ne + i];
  sval[pos] = adata[i];
}

// ---------------- attention: quarter-wave (4 edges/wave), depth-1 prefetch -
__global__ __launch_bounds__(256) void k_att_csr(
    const __half* __restrict__ Eb, const unsigned* __restrict__ wpk,
    const int* __restrict__ start, const int* __restrict__ scol,
    const int* __restrict__ srel, const __half* __restrict__ baseb,
    float alpha, __half* __restrict__ outb)
{
  int wave = threadIdx.x >> 6, lane = threadIdx.x & 63;
  int q = lane >> 4, ql = lane & 15;
  int row = blockIdx.x * 4 + wave;
  if (row >= KG_E) return;
  int s = start[row], e = start[row + 1];
  const uint2* erp = (const uint2*)(Eb + (size_t)row * E_DIM);
  __half2 zero2 = __floats2half2_rn(0.f, 0.f);
  __half2 er[5][2], ac[5][2];
  #pragma unroll
  for (int c = 0; c < 5; ++c) {
    int m = c * 16 + ql;
    if (m < NP2) {
      uint2 u = erp[m];
      er[c][0] = u2h2(u.x); er[c][1] = u2h2(u.y);
    } else { er[c][0] = zero2; er[c][1] = zero2; }
    ac[c][0] = zero2; ac[c][1] = zero2;
  }
  float rs = 0.f;
  int nIter = (e - s + 3) >> 2;

  bool actA = false; int relA = 0;
  uint2 CA[5];
  #pragma unroll
  for (int c = 0; c < 5; ++c) CA[c] = make_uint2(0u, 0u);
  {
    int j0 = s + q;
    if (nIter > 0 && j0 < e) {
      actA = true;
      int col = scol[j0]; relA = srel[j0];
      const uint2* ecp = (const uint2*)(Eb + (size_t)col * E_DIM);
      #pragma unroll
      for (int c = 0; c < 5; ++c) {
        int m = c * 16 + ql;
        if (m < NP2) CA[c] = ecp[m];
      }
    }
  }

  for (int it = 0; it < nIter; ++it) {
    bool actB = false; int relB = 0;
    uint2 CB[5];
    #pragma unroll
    for (int c = 0; c < 5; ++c) CB[c] = make_uint2(0u, 0u);
    {
      int jn = s + 4 * (it + 1) + q;
      if (it + 1 < nIter && jn < e) {
        actB = true;
        int col = scol[jn]; relB = srel[jn];
        const uint2* ecp = (const uint2*)(Eb + (size_t)col * E_DIM);
        #pragma unroll
        for (int c = 0; c < 5; ++c) {
          int m = c * 16 + ql;
          if (m < NP2) CB[c] = ecp[m];
        }
      }
    }
    const uint2* whp = (const uint2*)(wpk + (size_t)relA * NPAIR);
    const uint2* wtp = (const uint2*)(wpk + (size_t)(KG_R + relA) * NPAIR);
    __half2 p2a = zero2, p2b = zero2;
    #pragma unroll
    for (int c = 0; c < 5; ++c) {
      int m = c * 16 + ql;
      if (m < NP2) {
        uint2 uh = whp[m], ut = wtp[m];
        p2a = __hfma2(er[c][0], u2h2(uh.x), p2a);
        p2b = __hfma2(er[c][1], u2h2(uh.y), p2b);
        p2a = __hfma2(u2h2(CA[c].x), u2h2(ut.x), p2a);
        p2b = __hfma2(u2h2(CA[c].y), u2h2(ut.y), p2b);
      }
    }
    __half2 p2 = __hadd2(p2a, p2b);
    float p4 = __low2float(p2) + __high2float(p2);
    #pragma unroll
    for (int off = 8; off > 0; off >>= 1) p4 += __shfl_xor(p4, off, 64);
    float la = p4 >= 0.f ? p4 : LRELU * p4;
    float at = actA ? __expf(-la) : 0.f;
    rs += at;
    __half2 at2 = __float2half2_rn(at);
    #pragma unroll
    for (int c = 0; c < 5; ++c) {
      ac[c][0] = __hfma2(at2, u2h2(CA[c].x), ac[c][0]);
      ac[c][1] = __hfma2(at2, u2h2(CA[c].y), ac[c][1]);
    }
    actA = actB; relA = relB;
    #pragma unroll
    for (int c = 0; c < 5; ++c) CA[c] = CB[c];
  }
  // merge the four quarters
  rs += __shfl_xor(rs, 16, 64);
  rs += __shfl_xor(rs, 32, 64);
  #pragma unroll
  for (int c = 0; c < 5; ++c) {
    #pragma unroll
    for (int k = 0; k < 2; ++k) {
      unsigned o = __shfl_xor(h22u(ac[c][k]), 16, 64);
      ac[c][k] = __hadd2(ac[c][k], u2h2(o));
      o = __shfl_xor(h22u(ac[c][k]), 32, 64);
      ac[c][k] = __hadd2(ac[c][k], u2h2(o));
    }
  }
  if (q == 0) {
    float iv = (rs == 0.f) ? 0.f : 1.f / rs;
    const uint2* bp = (const uint2*)(baseb + (size_t)row * E_DIM);
    uint2* op = (uint2*)(outb + (size_t)row * E_DIM);
    #pragma unroll
    for (int c = 0; c < 5; ++c) {
      int m = c * 16 + ql;
      if (m < NP2) {
        uint2 ub = bp[m];
        float v0 = __low2float(ac[c][0]) * iv;  v0 = v0 > 0.f ? v0 : 0.f;
        float v1 = __high2float(ac[c][0]) * iv; v1 = v1 > 0.f ? v1 : 0.f;
        float v2 = __low2float(ac[c][1]) * iv;  v2 = v2 > 0.f ? v2 : 0.f;
        float v3 = __high2float(ac[c][1]) * iv; v3 = v3 > 0.f ? v3 : 0.f;
        uint2 o2;
        o2.x = packh(hlo(ub.x) + alpha * v0, hhi(ub.x) + alpha * v1);
        o2.y = packh(hlo(ub.y) + alpha * v2, hhi(ub.y) + alpha * v3);
        op[m] = o2;
      }
    }
  }
}

// ---------------- fused spmm + highway: quarter-wave, depth-1 prefetch -----
__global__ __launch_bounds__(256) void k_spmm_hw(
    const __half* __restrict__ Xb, const int* __restrict__ start,
    const int* __restrict__ scol, const float* __restrict__ sval,
    const __half* __restrict__ Gb, const __half* __restrict__ baseb,
    const float* __restrict__ br,
    __half* __restrict__ outb, float* __restrict__ outf)
{
  int wave = threadIdx.x >> 6, lane = threadIdx.x & 63;
  int q = lane >> 4, ql = lane & 15;
  int row = blockIdx.x * 4 + wave;
  if (row >= KG_E) return;
  int s = start[row], e = start[row + 1];
  float ac0[5], ac1[5], ac2[5], ac3[5];
  #pragma unroll
  for (int c = 0; c < 5; ++c) { ac0[c]=0.f; ac1[c]=0.f; ac2[c]=0.f; ac3[c]=0.f; }
  int nIter = (e - s + 3) >> 2;

  float vA = 0.f;
  uint2 XA[5];
  #pragma unroll
  for (int c = 0; c < 5; ++c) XA[c] = make_uint2(0u, 0u);
  {
    int j0 = s + q;
    if (nIter > 0 && j0 < e) {
      int col = scol[j0]; vA = sval[j0];
      const uint2* xp = (const uint2*)(Xb + (size_t)col * E_DIM);
      #pragma unroll
      for (int c = 0; c < 5; ++c) {
        int m = c * 16 + ql;
        if (m < NP2) XA[c] = xp[m];
      }
    }
  }
  for (int it = 0; it < nIter; ++it) {
    float vB = 0.f;
    uint2 XB[5];
    #pragma unroll
    for (int c = 0; c < 5; ++c) XB[c] = make_uint2(0u, 0u);
    {
      int jn = s + 4 * (it + 1) + q;
      if (it + 1 < nIter && jn < e) {
        int col = scol[jn]; vB = sval[jn];
        const uint2* xp = (const uint2*)(Xb + (size_t)col * E_DIM);
        #pragma unroll
        for (int c = 0; c < 5; ++c) {
          int m = c * 16 + ql;
          if (m < NP2) XB[c] = xp[m];
        }
      }
    }
    #pragma unroll
    for (int c = 0; c < 5; ++c) {
      ac0[c] += vA * hlo(XA[c].x); ac1[c] += vA * hhi(XA[c].x);
      ac2[c] += vA * hlo(XA[c].y); ac3[c] += vA * hhi(XA[c].y);
    }
    vA = vB;
    #pragma unroll
    for (int c = 0; c < 5; ++c) XA[c] = XB[c];
  }
  #pragma unroll
  for (int c = 0; c < 5; ++c) {
    ac0[c] += __shfl_xor(ac0[c], 16, 64); ac0[c] += __shfl_xor(ac0[c], 32, 64);
    ac1[c] += __shfl_xor(ac1[c], 16, 64); ac1[c] += __shfl_xor(ac1[c], 32, 64);
    ac2[c] += __shfl_xor(ac2[c], 16, 64); ac2[c] += __shfl_xor(ac2[c], 32, 64);
    ac3[c] += __shfl_xor(ac3[c], 16, 64); ac3[c] += __shfl_xor(ac3[c], 32, 64);
  }
  if (q == 0) {
    const uint2* gp = (const uint2*)(Gb + (size_t)row * E_DIM);
    const uint2* bp = (const uint2*)(baseb + (size_t)row * E_DIM);
    #pragma unroll
    for (int c = 0; c < 5; ++c) {
      int m = c * 16 + ql;
      if (m < NP2) {
        uint2 ug = gp[m], ub = bp[m];
        float4 b4 = ((const float4*)br)[m];
        float g0 = 1.f / (1.f + __expf(-(hlo(ug.x) + b4.x)));
        float g1 = 1.f / (1.f + __expf(-(hhi(ug.x) + b4.y)));
        float g2 = 1.f / (1.f + __expf(-(hlo(ug.y) + b4.z)));
        float g3 = 1.f / (1.f + __expf(-(hhi(ug.y) + b4.w)));
        float y0 = ac0[c] > 0.f ? ac0[c] : 0.f;
        float y1 = ac1[c] > 0.f ? ac1[c] : 0.f;
        float y2 = ac2[c] > 0.f ? ac2[c] : 0.f;
        float y3 = ac3[c] > 0.f ? ac3[c] : 0.f;
        float o0 = g0 * y0 + (1.f - g0) * hlo(ub.x);
        float o1 = g1 * y1 + (1.f - g1) * hhi(ub.x);
        float o2 = g2 * y2 + (1.f - g2) * hlo(ub.y);
        float o3 = g3 * y3 + (1.f - g3) * hhi(ub.y);
        if (outb) {
          uint2 ov;
          ov.x = packh(o0, o1); ov.y = packh(o2, o3);
          ((uint2*)(outb + (size_t)row * E_DIM))[m] = ov;
        } else {
          float4 of; of.x = o0; of.y = o1; of.z = o2; of.w = o3;
          ((float4*)(outf + (size_t)row * E_DIM))[m] = of;
        }
      }
    }
  }
}

// ---------------- pack W into MFMA B-fragment layout (fp16) ----------------
__global__ __launch_bounds__(64) void k_packW(
    const float* __restrict__ W1, const float* __restrict__ W2,
    __half* __restrict__ Wp)
{
  int lane = threadIdx.x;
  int t = blockIdx.x, s = blockIdx.y;
  int c = t * 16 + (lane & 15);
  __half v[8];
  #pragma unroll
  for (int j = 0; j < 8; ++j) {
    int k = s * 32 + (lane >> 4) * 8 + j;
    float x = 0.f;
    if (k < E_DIM && c < 2 * E_DIM)
      x = (c < E_DIM) ? W1[(size_t)k * E_DIM + c]
                      : W2[(size_t)k * E_DIM + (c - E_DIM)];
    v[j] = __float2half_rn(x);
  }
  size_t base = ((size_t)(t * NK + s) * 64 + lane) * 8;
  #pragma unroll
  for (int j = 0; j < 8; ++j) Wp[base + j] = v[j];
}

// ---------------- fused dual-GEMM: wave = 2 n-tiles x 2 M-subtiles ---------
__global__ __launch_bounds__(256) void k_gemm2_mfma(
    const __half* __restrict__ Xb, const __half* __restrict__ Wp,
    __half* __restrict__ Y1, __half* __restrict__ Y2, int M)
{
  __shared__ __half Xs[32][XS_LD];
  int tid = threadIdx.x;
  int r0 = blockIdx.x * 32;
  int nb = blockIdx.y;

  for (int t = tid; t < 32 * (XS_LD / 2); t += 256) {
    int r = t / (XS_LD / 2), u = t % (XS_LD / 2);
    unsigned v = 0;
    int rg = r0 + r;
    if (rg < M && u < E_DIM / 2) v = ((const unsigned*)Xb)[(size_t)rg * (E_DIM / 2) + u];
    ((unsigned*)&Xs[0][0])[r * (XS_LD / 2) + u] = v;
  }
  __syncthreads();

  int wid = tid >> 6, lane = tid & 63;
  int rowA = lane & 15;
  int kgrp = (lane >> 4) * 8;
  int tbase = nb * 8 + wid * 2;

  const f16x8* wf0 = (const f16x8*)Wp + (size_t)tbase * (NK * 64) + lane;
  const f16x8* wf1 = (const f16x8*)Wp + (size_t)(tbase + 1) * (NK * 64) + lane;

  f32x4 acc[2][2] = {{{0,0,0,0},{0,0,0,0}},{{0,0,0,0},{0,0,0,0}}};
  #pragma unroll 2
  for (int ks = 0; ks < NK; ++ks) {
    f16x8 a0 = *(const f16x8*)&Xs[rowA][ks * 32 + kgrp];
    f16x8 a1 = *(const f16x8*)&Xs[16 + rowA][ks * 32 + kgrp];
    f16x8 b0 = wf0[ks * 64];
    f16x8 b1 = wf1[ks * 64];
    acc[0][0] = __builtin_amdgcn_mfma_f32_16x16x32_f16(a0, b0, acc[0][0], 0, 0, 0);
    acc[0][1] = __builtin_amdgcn_mfma_f32_16x16x32_f16(a0, b1, acc[0][1], 0, 0, 0);
    acc[1][0] = __builtin_amdgcn_mfma_f32_16x16x32_f16(a1, b0, acc[1][0], 0, 0, 0);
    acc[1][1] = __builtin_amdgcn_mfma_f32_16x16x32_f16(a1, b1, acc[1][1], 0, 0, 0);
  }

  int rquad = (lane >> 4) << 2;
  #pragma unroll
  for (int mg = 0; mg < 2; ++mg) {
    #pragma unroll
    for (int nt = 0; nt < 2; ++nt) {
      int c = (tbase + nt) * 16 + (lane & 15);
      #pragma unroll
      for (int j = 0; j < 4; ++j) {
        int row = r0 + mg * 16 + rquad + j;
        if (row < M) {
          __half hv = __float2half_rn(acc[mg][nt][j]);
          if (c < E_DIM)            Y1[(size_t)row * E_DIM + c] = hv;
          else if (c < 2 * E_DIM)   Y2[(size_t)row * E_DIM + (c - E_DIM)] = hv;
        }
      }
    }
  }
}

extern "C" void kernel_launch(void* const* d_in, const int* in_sizes, int n_in,
                              void* d_out, int out_size, void* d_ws, size_t ws_size,
                              hipStream_t stream)
{
  const float* primal      = (const float*)d_in[0];
  const float* r_head      = (const float*)d_in[1];
  const float* r_tail      = (const float*)d_in[2];
  const float* e_adj_data  = (const float*)d_in[3];
  const float* be_L        = (const float*)d_in[4];
  const float* be_R        = (const float*)d_in[5];
  const float* atten_r     = (const float*)d_in[6];
  const float* gcnW1       = (const float*)d_in[7];
  const float* hwWr        = (const float*)d_in[8];
  const float* hwbr        = (const float*)d_in[9];
  const int*   e_adj_index = (const int*)d_in[10];
  const int*   eer_idx     = (const int*)d_in[11];
  const int*   eer_rel     = (const int*)d_in[12];
  int ne   = in_sizes[10] / 2;
  int neer = in_sizes[11] / 2;

  char* ws = (char*)d_ws;
  size_t off = 0;
  auto take = [&](size_t bytes) {
    void* p = ws + off;
    off = (off + bytes + 255) & ~(size_t)255;
    return p;
  };
  int*   cnt      = (int*)  take((size_t)2 * KG_R * sizeof(int));
  float* inv      = (float*)take((size_t)2 * KG_R * sizeof(float));
  size_t z0 = off;
  int*   hcntA    = (int*)  take((size_t)KG_E * sizeof(int));
  int*   hcntB    = (int*)  take((size_t)KG_E * sizeof(int));
  int*   hfillA   = (int*)  take((size_t)KG_E * sizeof(int));
  int*   hfillB   = (int*)  take((size_t)KG_E * sizeof(int));
  int*   rfill    = (int*)  take((size_t)2 * KG_R * sizeof(int));
  float* rsumb    = (float*)take((size_t)2 * KG_R * sizeof(float));
  size_t z1 = off;
  int*   lidx     = (int*)  take((size_t)2 * KG_R * CAP * sizeof(int));
  float* lsv      = (float*)take((size_t)2 * KG_R * CAP * sizeof(float));
  unsigned* wpk   = (unsigned*)take((size_t)2 * KG_R * NPAIR * sizeof(unsigned));
  int*   bsum     = (int*)  take((size_t)2 * (NB_SCAN + 1) * sizeof(int));
  int*   eer_start= (int*)  take((size_t)(KG_E + 4) * sizeof(int));
  int*   adj_start= (int*)  take((size_t)(KG_E + 4) * sizeof(int));
  int*   eer_scol = (int*)  take((size_t)neer * sizeof(int));
  int*   eer_srel = (int*)  take((size_t)neer * sizeof(int));
  int*   adj_scol = (int*)  take((size_t)ne * sizeof(int));
  float* adj_sval = (float*)take((size_t)ne * sizeof(float));
  __half* Wp = (__half*)take((size_t)NT * NK * 64 * 8 * sizeof(__half));
  __half* B0 = (__half*)take((size_t)KG_E * E_DIM * sizeof(__half));
  __half* B1 = (__half*)take((size_t)KG_E * E_DIM * sizeof(__half));
  __half* B2 = (__half*)take((size_t)KG_E * E_DIM * sizeof(__half));
  __half* Fb = (__half*)take((size_t)KG_E * E_DIM * sizeof(__half));
  __half* Gb = (__half*)take((size_t)KG_E * E_DIM * sizeof(__half));
  float* out      = (float*)d_out;
  (void)ws_size; (void)n_in; (void)out_size;

  int eg = (neer + 255) / 256;
  int ag = (ne + 255) / 256;

  hipMemsetAsync(ws + z0, 0, z1 - z0, stream);

  k_hist<<<eg, 256, 0, stream>>>(eer_idx, hcntA, neer);
  k_hist<<<ag, 256, 0, stream>>>(e_adj_index, hcntB, ne);
  k_scan_a<<<dim3(NB_SCAN, 2), 256, 0, stream>>>(hcntA, hcntB, bsum, KG_E);
  k_scan_b<<<1, 64, 0, stream>>>(bsum);
  k_scan_c<<<dim3(NB_SCAN, 2), 256, 0, stream>>>(hcntA, hcntB, bsum,
                                                 eer_start, adj_start, KG_E);
  k_scatter_eer<<<eg, 256, 0, stream>>>(eer_idx, eer_rel, eer_start, hfillA,
                                        eer_scol, eer_srel, neer);
  k_scatter_adj<<<ag, 256, 0, stream>>>(e_adj_index, e_adj_data, adj_start, hfillB,
                                        adj_scol, adj_sval, ne);

  k_compact2<<<dim3(NCH, KG_R, 2), 256, 0, stream>>>(r_head, r_tail, be_L, be_R,
                                                     lidx, lsv, rfill, rsumb);
  k_rmeta<<<(2 * KG_R + 255) / 256, 256, 0, stream>>>(rfill, rsumb, cnt, inv);
  k_packW<<<dim3(NT, NK), 64, 0, stream>>>(gcnW1, hwWr, Wp);
  int n4 = KG_E * E_DIM / 4;
  k_toh<<<(n4 + 255) / 256, 256, 0, stream>>>(primal, B0, n4);

  int rg = (KG_E + 3) / 4;

  k_rlayer<<<2 * KG_R, 192, 0, stream>>>(B0, lidx, lsv, cnt, inv, atten_r, wpk);
  k_att_csr<<<rg, 256, 0, stream>>>(B0, wpk, eer_start, eer_scol, eer_srel,
                                    B0, 0.1f, B1);
  k_rlayer<<<2 * KG_R, 192, 0, stream>>>(B1, lidx, lsv, cnt, inv, atten_r, wpk);
  k_att_csr<<<rg, 256, 0, stream>>>(B1, wpk, eer_start, eer_scol, eer_srel,
                                    B0, 0.3f, B2);

  dim3 gg((KG_E + 31) / 32, 5);
  k_gemm2_mfma<<<gg, 256, 0, stream>>>(B2, Wp, Fb, Gb, KG_E);
  k_spmm_hw<<<rg, 256, 0, stream>>>(Fb, adj_start, adj_scol, adj_sval,
                                    Gb, B2, hwbr, B1, (float*)nullptr);

  k_gemm2_mfma<<<gg, 256, 0, stream>>>(B1, Wp, Fb, Gb, KG_E);
  k_spmm_hw<<<rg, 256, 0, stream>>>(Fb, adj_start, adj_scol, adj_sval,
                                    Gb, B1, hwbr, (__half*)nullptr, out);
}

// Round 19
// 729.843 us; speedup vs baseline: 1.0408x; 1.0408x over previous
//
#include <hip/hip_runtime.h>
#include <hip/hip_fp16.h>
#include <math.h>

#define KG_E  50000
#define KG_R  500
#define E_DIM 300
#define NPAIR 150
#define NP2   75
#define CAP   1024
#define LRELU 0.2f

#define NK    10
#define NT    40
#define XS_LD 328

#define NB_SCAN 49

typedef __attribute__((ext_vector_type(8))) _Float16 f16x8;
typedef __attribute__((ext_vector_type(4))) float f32x4;

__device__ __forceinline__ __half2 u2h2(unsigned u) {
  union { unsigned u; __half2 h; } v; v.u = u; return v.h;
}
__device__ __forceinline__ unsigned h22u(__half2 h) {
  union { unsigned u; __half2 h; } v; v.h = h; return v.u;
}
__device__ __forceinline__ float hlo(unsigned u) { return __low2float(u2h2(u)); }
__device__ __forceinline__ float hhi(unsigned u) { return __high2float(u2h2(u)); }
__device__ __forceinline__ unsigned packh(float lo, float hi) {
  return h22u(__floats2half2_rn(lo, hi));
}

// ---------------- f32 -> fp16 table conversion -----------------------------
__global__ __launch_bounds__(256) void k_toh(
    const float* __restrict__ src, __half* __restrict__ dst, int n4)
{
  int i = blockIdx.x * 256 + threadIdx.x;
  if (i >= n4) return;
  float4 f = ((const float4*)src)[i];
  uint2 o;
  o.x = packh(f.x, f.y);
  o.y = packh(f.z, f.w);
  ((uint2*)dst)[i] = o;
}

// ---------------- compaction: 20 floats/thread, 10k blocks -----------------
#define NCH 10
#define SCAP 1024
#define NF4 1250
__global__ __launch_bounds__(256) void k_compact2(
    const float* __restrict__ r_head, const float* __restrict__ r_tail,
    const float* __restrict__ be_L, const float* __restrict__ be_R,
    int* __restrict__ lidx, float* __restrict__ lsval,
    int* __restrict__ fill, float* __restrict__ rsum)
{
  __shared__ int   ls_e[SCAP];
  __shared__ float ls_v[SCAP];
  __shared__ int   ls_cnt;
  __shared__ float ls_sum;
  __shared__ int   ls_base;
  int m = blockIdx.z;
  int r = blockIdx.y;
  const float* rowp = (m ? r_tail : r_head) + (size_t)r * KG_E;
  const float* be   = m ? be_R : be_L;
  int slot = m * KG_R + r;
  int lane = threadIdx.x & 63;
  if (threadIdx.x == 0) { ls_cnt = 0; ls_sum = 0.f; }
  __syncthreads();

  const int CH = KG_E / NCH;
  int c0 = blockIdx.x * CH;
  const float4* rp4 = (const float4*)(rowp + c0);

  float vals[20];
  #pragma unroll
  for (int t = 0; t < 5; ++t) {
    int fi = t * 256 + threadIdx.x;
    float4 f = (fi < NF4) ? rp4[fi] : make_float4(0.f, 0.f, 0.f, 0.f);
    vals[t*4+0] = f.x; vals[t*4+1] = f.y; vals[t*4+2] = f.z; vals[t*4+3] = f.w;
  }
  float lsum = 0.f;
  int cnt = 0;
  #pragma unroll
  for (int q = 0; q < 20; ++q) {
    lsum += vals[q];
    cnt += (vals[q] != 0.f) ? 1 : 0;
  }
  int pre = cnt;
  #pragma unroll
  for (int off = 1; off < 64; off <<= 1) {
    int u = __shfl_up(pre, off, 64);
    if (lane >= off) pre += u;
  }
  int wave_base = 0;
  if (lane == 63 && pre > 0) wave_base = atomicAdd(&ls_cnt, pre);
  wave_base = __shfl(wave_base, 63, 64);
  if (cnt > 0) {
    int o = wave_base + pre - cnt;
    #pragma unroll
    for (int t = 0; t < 5; ++t) {
      int fi = t * 256 + threadIdx.x;
      #pragma unroll
      for (int q = 0; q < 4; ++q) {
        float v = vals[t*4+q];
        if (v != 0.f) {
          if (o < SCAP) {
            int e = c0 + fi * 4 + q;
            ls_e[o] = e;
            ls_v[o] = v * be[e];
          }
          ++o;
        }
      }
    }
  }
  #pragma unroll
  for (int off = 32; off > 0; off >>= 1) lsum += __shfl_xor(lsum, off, 64);
  if (lane == 0 && lsum != 0.f) atomicAdd(&ls_sum, lsum);
  __syncthreads();

  int total = ls_cnt < SCAP ? ls_cnt : SCAP;
  if (threadIdx.x == 0) {
    ls_base = atomicAdd(&fill[slot], total);
    if (ls_sum != 0.f) atomicAdd(&rsum[slot], ls_sum);
  }
  __syncthreads();
  int gbase = ls_base;
  int*   li = lidx  + (size_t)slot * CAP;
  float* lv = lsval + (size_t)slot * CAP;
  for (int i = threadIdx.x; i < total; i += 256) {
    int pos = gbase + i;
    if (pos < CAP) { li[pos] = ls_e[i]; lv[pos] = ls_v[i]; }
  }
}

__global__ __launch_bounds__(256) void k_rmeta(
    const int* __restrict__ fill, const float* __restrict__ rsum,
    int* __restrict__ cnt, float* __restrict__ inv)
{
  int i = blockIdx.x * 256 + threadIdx.x;
  if (i < 2 * KG_R) {
    int c = fill[i];
    cnt[i] = c > CAP ? CAP : c;
    float s = rsum[i];
    inv[i] = (s == 0.f) ? 0.f : 1.f / s;
  }
}

// ---------------- r-layer ---------------------------------------------------
__global__ __launch_bounds__(192) void k_rlayer(
    const __half* __restrict__ Eb, const int* __restrict__ lidx,
    const float* __restrict__ lsval, const int* __restrict__ cnt,
    const float* __restrict__ inv, const float* __restrict__ atten,
    unsigned* __restrict__ wpk)
{
  int b = blockIdx.x;
  int m = b / KG_R, r = b % KG_R;
  int p = threadIdx.x;
  if (p >= NPAIR) return;
  int slot = m * KG_R + r;
  int n = cnt[slot];
  const int*   li = lidx  + (size_t)slot * CAP;
  const float* lv = lsval + (size_t)slot * CAP;
  float alo = 0.f, ahi = 0.f;
  #pragma unroll 4
  for (int i = 0; i < n; ++i) {
    int e = li[i];
    float s = lv[i];
    unsigned u = ((const unsigned*)(Eb + (size_t)e * E_DIM))[p];
    alo += s * hlo(u);
    ahi += s * hhi(u);
  }
  float iv = inv[slot];
  float vlo = alo * iv; vlo = vlo > 0.f ? vlo : 0.f;
  float vhi = ahi * iv; vhi = vhi > 0.f ? vhi : 0.f;
  vlo *= atten[m * E_DIM + 2 * p];
  vhi *= atten[m * E_DIM + 2 * p + 1];
  wpk[(size_t)slot * NPAIR + p] = packh(vlo, vhi);
}

// ---------------- CSR build -------------------------------------------------
__global__ __launch_bounds__(256) void k_hist(
    const int* __restrict__ rows, int* __restrict__ cnt, int n)
{
  int i = blockIdx.x * 256 + threadIdx.x;
  if (i < n) atomicAdd(&cnt[rows[i]], 1);
}

__global__ __launch_bounds__(256) void k_scan_a(
    const int* __restrict__ c0, const int* __restrict__ c1,
    int* __restrict__ bsum, int n)
{
  const int* c = blockIdx.y ? c1 : c0;
  int base = blockIdx.x * 1024;
  int s = 0;
  #pragma unroll
  for (int k = 0; k < 4; ++k) {
    int i = base + k * 256 + threadIdx.x;
    if (i < n) s += c[i];
  }
  #pragma unroll
  for (int off = 32; off > 0; off >>= 1) s += __shfl_xor(s, off, 64);
  __shared__ int ws[4];
  if ((threadIdx.x & 63) == 0) ws[threadIdx.x >> 6] = s;
  __syncthreads();
  if (threadIdx.x == 0)
    bsum[blockIdx.y * (NB_SCAN + 1) + blockIdx.x] = ws[0] + ws[1] + ws[2] + ws[3];
}

__global__ __launch_bounds__(64) void k_scan_b(int* __restrict__ bsum)
{
  if (threadIdx.x < 2) {
    int* b = bsum + threadIdx.x * (NB_SCAN + 1);
    int acc = 0;
    for (int i = 0; i < NB_SCAN; ++i) { int v = b[i]; b[i] = acc; acc += v; }
    b[NB_SCAN] = acc;
  }
}

__global__ __launch_bounds__(256) void k_scan_c(
    const int* __restrict__ c0, const int* __restrict__ c1,
    const int* __restrict__ bsum,
    int* __restrict__ s0, int* __restrict__ s1, int n)
{
  const int* c = blockIdx.y ? c1 : c0;
  int* sO = blockIdx.y ? s1 : s0;
  if (blockIdx.x == 0 && threadIdx.x == 0)
    sO[n] = bsum[blockIdx.y * (NB_SCAN + 1) + NB_SCAN];
  int boff = bsum[blockIdx.y * (NB_SCAN + 1) + blockIdx.x];
  int i0 = blockIdx.x * 1024 + threadIdx.x * 4;
  int4 v = {0, 0, 0, 0};
  if (i0 < n) v = ((const int4*)c)[i0 >> 2];
  int tsum = v.x + v.y + v.z + v.w;
  int lane = threadIdx.x & 63, wid = threadIdx.x >> 6;
  int inc = tsum;
  #pragma unroll
  for (int off = 1; off < 64; off <<= 1) {
    int u = __shfl_up(inc, off, 64);
    if (lane >= off) inc += u;
  }
  __shared__ int ws[4];
  if (lane == 63) ws[wid] = inc;
  __syncthreads();
  int woff = 0;
  if (wid > 0) woff += ws[0];
  if (wid > 1) woff += ws[1];
  if (wid > 2) woff += ws[2];
  int ex = boff + woff + inc - tsum;
  if (i0 < n) {
    int4 o;
    o.x = ex; o.y = ex + v.x; o.z = o.y + v.y; o.w = o.z + v.z;
    ((int4*)sO)[i0 >> 2] = o;
  }
}

__global__ __launch_bounds__(256) void k_scatter_eer(
    const int* __restrict__ eidx, const int* __restrict__ erel,
    const int* __restrict__ start, int* __restrict__ fill,
    int* __restrict__ scol, int* __restrict__ srel, int neer)
{
  int i = blockIdx.x * 256 + threadIdx.x;
  if (i >= neer) return;
  int row = eidx[i];
  int pos = start[row] + atomicAdd(&fill[row], 1);
  scol[pos] = eidx[neer + i];
  srel[pos] = erel[i];
}

__global__ __launch_bounds__(256) void k_scatter_adj(
    const int* __restrict__ aidx, const float* __restrict__ adata,
    const int* __restrict__ start, int* __restrict__ fill,
    int* __restrict__ scol, float* __restrict__ sval, int ne)
{
  int i = blockIdx.x * 256 + threadIdx.x;
  if (i >= ne) return;
  int row = aidx[i];
  int pos = start[row] + atomicAdd(&fill[row], 1);
  scol[pos] = aidx[ne + i];
  sval[pos] = adata[i];
}

// ---------------- attention: half-wave, fp16 math, depth-1 prefetch --------
__global__ __launch_bounds__(256) void k_att_csr(
    const __half* __restrict__ Eb, const unsigned* __restrict__ wpk,
    const int* __restrict__ start, const int* __restrict__ scol,
    const int* __restrict__ srel, const __half* __restrict__ baseb,
    float alpha, __half* __restrict__ outb)
{
  int wave = threadIdx.x >> 6, lane = threadIdx.x & 63;
  int half = lane >> 5, hl = lane & 31;
  int row = blockIdx.x * 4 + wave;
  if (row >= KG_E) return;
  int s = start[row], e = start[row + 1];
  const uint2* erp = (const uint2*)(Eb + (size_t)row * E_DIM);
  __half2 zero2 = __floats2half2_rn(0.f, 0.f);
  __half2 er[3][2], ac[3][2];
  #pragma unroll
  for (int c = 0; c < 3; ++c) {
    int m = c * 32 + hl;
    if (m < NP2) {
      uint2 u = erp[m];
      er[c][0] = u2h2(u.x); er[c][1] = u2h2(u.y);
    } else { er[c][0] = zero2; er[c][1] = zero2; }
    ac[c][0] = zero2; ac[c][1] = zero2;
  }
  float rs = 0.f;
  int nIter = (e - s + 1) >> 1;

  bool actA = false; int relA = 0;
  uint2 CA[3];
  #pragma unroll
  for (int c = 0; c < 3; ++c) CA[c] = make_uint2(0u, 0u);
  {
    int j0 = s + half;
    if (nIter > 0 && j0 < e) {
      actA = true;
      int col = scol[j0]; relA = srel[j0];
      const uint2* ecp = (const uint2*)(Eb + (size_t)col * E_DIM);
      #pragma unroll
      for (int c = 0; c < 3; ++c) {
        int m = c * 32 + hl;
        if (m < NP2) CA[c] = ecp[m];
      }
    }
  }

  for (int it = 0; it < nIter; ++it) {
    bool actB = false; int relB = 0;
    uint2 CB[3];
    #pragma unroll
    for (int c = 0; c < 3; ++c) CB[c] = make_uint2(0u, 0u);
    {
      int jn = s + 2 * (it + 1) + half;
      if (it + 1 < nIter && jn < e) {
        actB = true;
        int col = scol[jn]; relB = srel[jn];
        const uint2* ecp = (const uint2*)(Eb + (size_t)col * E_DIM);
        #pragma unroll
        for (int c = 0; c < 3; ++c) {
          int m = c * 32 + hl;
          if (m < NP2) CB[c] = ecp[m];
        }
      }
    }
    const uint2* whp = (const uint2*)(wpk + (size_t)relA * NPAIR);
    const uint2* wtp = (const uint2*)(wpk + (size_t)(KG_R + relA) * NPAIR);
    __half2 p2a = zero2, p2b = zero2;
    #pragma unroll
    for (int c = 0; c < 3; ++c) {
      int m = c * 32 + hl;
      if (m < NP2) {
        uint2 uh = whp[m], ut = wtp[m];
        p2a = __hfma2(er[c][0], u2h2(uh.x), p2a);
        p2b = __hfma2(er[c][1], u2h2(uh.y), p2b);
        p2a = __hfma2(u2h2(CA[c].x), u2h2(ut.x), p2a);
        p2b = __hfma2(u2h2(CA[c].y), u2h2(ut.y), p2b);
      }
    }
    __half2 p2 = __hadd2(p2a, p2b);
    float p4 = __low2float(p2) + __high2float(p2);
    #pragma unroll
    for (int off = 16; off > 0; off >>= 1) p4 += __shfl_xor(p4, off, 64);
    float la = p4 >= 0.f ? p4 : LRELU * p4;
    float at = actA ? __expf(-la) : 0.f;
    rs += at;
    __half2 at2 = __float2half2_rn(at);
    #pragma unroll
    for (int c = 0; c < 3; ++c) {
      ac[c][0] = __hfma2(at2, u2h2(CA[c].x), ac[c][0]);
      ac[c][1] = __hfma2(at2, u2h2(CA[c].y), ac[c][1]);
    }
    actA = actB; relA = relB;
    #pragma unroll
    for (int c = 0; c < 3; ++c) CA[c] = CB[c];
  }
  rs += __shfl_xor(rs, 32, 64);
  #pragma unroll
  for (int c = 0; c < 3; ++c) {
    #pragma unroll
    for (int k = 0; k < 2; ++k) {
      unsigned o = __shfl_xor(h22u(ac[c][k]), 32, 64);
      ac[c][k] = __hadd2(ac[c][k], u2h2(o));
    }
  }
  if (half == 0) {
    float iv = (rs == 0.f) ? 0.f : 1.f / rs;
    const uint2* bp = (const uint2*)(baseb + (size_t)row * E_DIM);
    uint2* op = (uint2*)(outb + (size_t)row * E_DIM);
    #pragma unroll
    for (int c = 0; c < 3; ++c) {
      int m = c * 32 + hl;
      if (m < NP2) {
        uint2 ub = bp[m];
        float v0 = __low2float(ac[c][0]) * iv;  v0 = v0 > 0.f ? v0 : 0.f;
        float v1 = __high2float(ac[c][0]) * iv; v1 = v1 > 0.f ? v1 : 0.f;
        float v2 = __low2float(ac[c][1]) * iv;  v2 = v2 > 0.f ? v2 : 0.f;
        float v3 = __high2float(ac[c][1]) * iv; v3 = v3 > 0.f ? v3 : 0.f;
        uint2 o2;
        o2.x = packh(hlo(ub.x) + alpha * v0, hhi(ub.x) + alpha * v1);
        o2.y = packh(hlo(ub.y) + alpha * v2, hhi(ub.y) + alpha * v3);
        op[m] = o2;
      }
    }
  }
}

// ---------------- fused spmm + highway: half-wave, depth-1 prefetch --------
__global__ __launch_bounds__(256) void k_spmm_hw(
    const __half* __restrict__ Xb, const int* __restrict__ start,
    const int* __restrict__ scol, const float* __restrict__ sval,
    const __half* __restrict__ Gb, const __half* __restrict__ baseb,
    const float* __restrict__ br,
    __half* __restrict__ outb, float* __restrict__ outf)
{
  int wave = threadIdx.x >> 6, lane = threadIdx.x & 63;
  int half = lane >> 5, hl = lane & 31;
  int row = blockIdx.x * 4 + wave;
  if (row >= KG_E) return;
  int s = start[row], e = start[row + 1];
  float ac0[3] = {0,0,0}, ac1[3] = {0,0,0}, ac2[3] = {0,0,0}, ac3[3] = {0,0,0};
  int nIter = (e - s + 1) >> 1;

  float vA = 0.f;
  uint2 XA[3];
  #pragma unroll
  for (int c = 0; c < 3; ++c) XA[c] = make_uint2(0u, 0u);
  {
    int j0 = s + half;
    if (nIter > 0 && j0 < e) {
      int col = scol[j0]; vA = sval[j0];
      const uint2* xp = (const uint2*)(Xb + (size_t)col * E_DIM);
      #pragma unroll
      for (int c = 0; c < 3; ++c) {
        int m = c * 32 + hl;
        if (m < NP2) XA[c] = xp[m];
      }
    }
  }
  for (int it = 0; it < nIter; ++it) {
    float vB = 0.f;
    uint2 XB[3];
    #pragma unroll
    for (int c = 0; c < 3; ++c) XB[c] = make_uint2(0u, 0u);
    {
      int jn = s + 2 * (it + 1) + half;
      if (it + 1 < nIter && jn < e) {
        int col = scol[jn]; vB = sval[jn];
        const uint2* xp = (const uint2*)(Xb + (size_t)col * E_DIM);
        #pragma unroll
        for (int c = 0; c < 3; ++c) {
          int m = c * 32 + hl;
          if (m < NP2) XB[c] = xp[m];
        }
      }
    }
    #pragma unroll
    for (int c = 0; c < 3; ++c) {
      ac0[c] += vA * hlo(XA[c].x); ac1[c] += vA * hhi(XA[c].x);
      ac2[c] += vA * hlo(XA[c].y); ac3[c] += vA * hhi(XA[c].y);
    }
    vA = vB;
    #pragma unroll
    for (int c = 0; c < 3; ++c) XA[c] = XB[c];
  }
  #pragma unroll
  for (int c = 0; c < 3; ++c) {
    ac0[c] += __shfl_xor(ac0[c], 32, 64);
    ac1[c] += __shfl_xor(ac1[c], 32, 64);
    ac2[c] += __shfl_xor(ac2[c], 32, 64);
    ac3[c] += __shfl_xor(ac3[c], 32, 64);
  }
  if (half == 0) {
    const uint2* gp = (const uint2*)(Gb + (size_t)row * E_DIM);
    const uint2* bp = (const uint2*)(baseb + (size_t)row * E_DIM);
    #pragma unroll
    for (int c = 0; c < 3; ++c) {
      int m = c * 32 + hl;
      if (m < NP2) {
        uint2 ug = gp[m], ub = bp[m];
        float4 b4 = ((const float4*)br)[m];
        float g0 = 1.f / (1.f + __expf(-(hlo(ug.x) + b4.x)));
        float g1 = 1.f / (1.f + __expf(-(hhi(ug.x) + b4.y)));
        float g2 = 1.f / (1.f + __expf(-(hlo(ug.y) + b4.z)));
        float g3 = 1.f / (1.f + __expf(-(hhi(ug.y) + b4.w)));
        float y0 = ac0[c] > 0.f ? ac0[c] : 0.f;
        float y1 = ac1[c] > 0.f ? ac1[c] : 0.f;
        float y2 = ac2[c] > 0.f ? ac2[c] : 0.f;
        float y3 = ac3[c] > 0.f ? ac3[c] : 0.f;
        float o0 = g0 * y0 + (1.f - g0) * hlo(ub.x);
        float o1 = g1 * y1 + (1.f - g1) * hhi(ub.x);
        float o2 = g2 * y2 + (1.f - g2) * hlo(ub.y);
        float o3 = g3 * y3 + (1.f - g3) * hhi(ub.y);
        if (outb) {
          uint2 ov;
          ov.x = packh(o0, o1); ov.y = packh(o2, o3);
          ((uint2*)(outb + (size_t)row * E_DIM))[m] = ov;
        } else {
          float4 of; of.x = o0; of.y = o1; of.z = o2; of.w = o3;
          ((float4*)(outf + (size_t)row * E_DIM))[m] = of;
        }
      }
    }
  }
}

// ---------------- pack W into MFMA B-fragment layout (fp16) ----------------
__global__ __launch_bounds__(64) void k_packW(
    const float* __restrict__ W1, const float* __restrict__ W2,
    __half* __restrict__ Wp)
{
  int lane = threadIdx.x;
  int t = blockIdx.x, s = blockIdx.y;
  int c = t * 16 + (lane & 15);
  __half v[8];
  #pragma unroll
  for (int j = 0; j < 8; ++j) {
    int k = s * 32 + (lane >> 4) * 8 + j;
    float x = 0.f;
    if (k < E_DIM && c < 2 * E_DIM)
      x = (c < E_DIM) ? W1[(size_t)k * E_DIM + c]
                      : W2[(size_t)k * E_DIM + (c - E_DIM)];
    v[j] = __float2half_rn(x);
  }
  size_t base = ((size_t)(t * NK + s) * 64 + lane) * 8;
  #pragma unroll
  for (int j = 0; j < 8; ++j) Wp[base + j] = v[j];
}

// ---------------- fused dual-GEMM: wave = 2 n-tiles x 2 M-subtiles ---------
__global__ __launch_bounds__(256) void k_gemm2_mfma(
    const __half* __restrict__ Xb, const __half* __restrict__ Wp,
    __half* __restrict__ Y1, __half* __restrict__ Y2, int M)
{
  __shared__ __half Xs[32][XS_LD];
  int tid = threadIdx.x;
  int r0 = blockIdx.x * 32;
  int nb = blockIdx.y;

  for (int t = tid; t < 32 * (XS_LD / 2); t += 256) {
    int r = t / (XS_LD / 2), u = t % (XS_LD / 2);
    unsigned v = 0;
    int rg = r0 + r;
    if (rg < M && u < E_DIM / 2) v = ((const unsigned*)Xb)[(size_t)rg * (E_DIM / 2) + u];
    ((unsigned*)&Xs[0][0])[r * (XS_LD / 2) + u] = v;
  }
  __syncthreads();

  int wid = tid >> 6, lane = tid & 63;
  int rowA = lane & 15;
  int kgrp = (lane >> 4) * 8;
  int tbase = nb * 8 + wid * 2;

  const f16x8* wf0 = (const f16x8*)Wp + (size_t)tbase * (NK * 64) + lane;
  const f16x8* wf1 = (const f16x8*)Wp + (size_t)(tbase + 1) * (NK * 64) + lane;

  f32x4 acc[2][2] = {{{0,0,0,0},{0,0,0,0}},{{0,0,0,0},{0,0,0,0}}};
  #pragma unroll 2
  for (int ks = 0; ks < NK; ++ks) {
    f16x8 a0 = *(const f16x8*)&Xs[rowA][ks * 32 + kgrp];
    f16x8 a1 = *(const f16x8*)&Xs[16 + rowA][ks * 32 + kgrp];
    f16x8 b0 = wf0[ks * 64];
    f16x8 b1 = wf1[ks * 64];
    acc[0][0] = __builtin_amdgcn_mfma_f32_16x16x32_f16(a0, b0, acc[0][0], 0, 0, 0);
    acc[0][1] = __builtin_amdgcn_mfma_f32_16x16x32_f16(a0, b1, acc[0][1], 0, 0, 0);
    acc[1][0] = __builtin_amdgcn_mfma_f32_16x16x32_f16(a1, b0, acc[1][0], 0, 0, 0);
    acc[1][1] = __builtin_amdgcn_mfma_f32_16x16x32_f16(a1, b1, acc[1][1], 0, 0, 0);
  }

  int rquad = (lane >> 4) << 2;
  #pragma unroll
  for (int mg = 0; mg < 2; ++mg) {
    #pragma unroll
    for (int nt = 0; nt < 2; ++nt) {
      int c = (tbase + nt) * 16 + (lane & 15);
      #pragma unroll
      for (int j = 0; j < 4; ++j) {
        int row = r0 + mg * 16 + rquad + j;
        if (row < M) {
          __half hv = __float2half_rn(acc[mg][nt][j]);
          if (c < E_DIM)            Y1[(size_t)row * E_DIM + c] = hv;
          else if (c < 2 * E_DIM)   Y2[(size_t)row * E_DIM + (c - E_DIM)] = hv;
        }
      }
    }
  }
}

extern "C" void kernel_launch(void* const* d_in, const int* in_sizes, int n_in,
                              void* d_out, int out_size, void* d_ws, size_t ws_size,
                              hipStream_t stream)
{
  const float* primal      = (const float*)d_in[0];
  const float* r_head      = (const float*)d_in[1];
  const float* r_tail      = (const float*)d_in[2];
  const float* e_adj_data  = (const float*)d_in[3];
  const float* be_L        = (const float*)d_in[4];
  const float* be_R        = (const float*)d_in[5];
  const float* atten_r     = (const float*)d_in[6];
  const float* gcnW1       = (const float*)d_in[7];
  const float* hwWr        = (const float*)d_in[8];
  const float* hwbr        = (const float*)d_in[9];
  const int*   e_adj_index = (const int*)d_in[10];
  const int*   eer_idx     = (const int*)d_in[11];
  const int*   eer_rel     = (const int*)d_in[12];
  int ne   = in_sizes[10] / 2;
  int neer = in_sizes[11] / 2;

  char* ws = (char*)d_ws;
  size_t off = 0;
  auto take = [&](size_t bytes) {
    void* p = ws + off;
    off = (off + bytes + 255) & ~(size_t)255;
    return p;
  };
  int*   cnt      = (int*)  take((size_t)2 * KG_R * sizeof(int));
  float* inv      = (float*)take((size_t)2 * KG_R * sizeof(float));
  size_t z0 = off;
  int*   hcntA    = (int*)  take((size_t)KG_E * sizeof(int));
  int*   hcntB    = (int*)  take((size_t)KG_E * sizeof(int));
  int*   hfillA   = (int*)  take((size_t)KG_E * sizeof(int));
  int*   hfillB   = (int*)  take((size_t)KG_E * sizeof(int));
  int*   rfill    = (int*)  take((size_t)2 * KG_R * sizeof(int));
  float* rsumb    = (float*)take((size_t)2 * KG_R * sizeof(float));
  size_t z1 = off;
  int*   lidx     = (int*)  take((size_t)2 * KG_R * CAP * sizeof(int));
  float* lsv      = (float*)take((size_t)2 * KG_R * CAP * sizeof(float));
  unsigned* wpk   = (unsigned*)take((size_t)2 * KG_R * NPAIR * sizeof(unsigned));
  int*   bsum     = (int*)  take((size_t)2 * (NB_SCAN + 1) * sizeof(int));
  int*   eer_start= (int*)  take((size_t)(KG_E + 4) * sizeof(int));
  int*   adj_start= (int*)  take((size_t)(KG_E + 4) * sizeof(int));
  int*   eer_scol = (int*)  take((size_t)neer * sizeof(int));
  int*   eer_srel = (int*)  take((size_t)neer * sizeof(int));
  int*   adj_scol = (int*)  take((size_t)ne * sizeof(int));
  float* adj_sval = (float*)take((size_t)ne * sizeof(float));
  __half* Wp = (__half*)take((size_t)NT * NK * 64 * 8 * sizeof(__half));
  __half* B0 = (__half*)take((size_t)KG_E * E_DIM * sizeof(__half));
  __half* B1 = (__half*)take((size_t)KG_E * E_DIM * sizeof(__half));
  __half* B2 = (__half*)take((size_t)KG_E * E_DIM * sizeof(__half));
  __half* Fb = (__half*)take((size_t)KG_E * E_DIM * sizeof(__half));
  __half* Gb = (__half*)take((size_t)KG_E * E_DIM * sizeof(__half));
  float* out      = (float*)d_out;
  (void)ws_size; (void)n_in; (void)out_size;

  int eg = (neer + 255) / 256;
  int ag = (ne + 255) / 256;

  hipMemsetAsync(ws + z0, 0, z1 - z0, stream);

  k_hist<<<eg, 256, 0, stream>>>(eer_idx, hcntA, neer);
  k_hist<<<ag, 256, 0, stream>>>(e_adj_index, hcntB, ne);
  k_scan_a<<<dim3(NB_SCAN, 2), 256, 0, stream>>>(hcntA, hcntB, bsum, KG_E);
  k_scan_b<<<1, 64, 0, stream>>>(bsum);
  k_scan_c<<<dim3(NB_SCAN, 2), 256, 0, stream>>>(hcntA, hcntB, bsum,
                                                 eer_start, adj_start, KG_E);
  k_scatter_eer<<<eg, 256, 0, stream>>>(eer_idx, eer_rel, eer_start, hfillA,
                                        eer_scol, eer_srel, neer);
  k_scatter_adj<<<ag, 256, 0, stream>>>(e_adj_index, e_adj_data, adj_start, hfillB,
                                        adj_scol, adj_sval, ne);

  k_compact2<<<dim3(NCH, KG_R, 2), 256, 0, stream>>>(r_head, r_tail, be_L, be_R,
                                                     lidx, lsv, rfill, rsumb);
  k_rmeta<<<(2 * KG_R + 255) / 256, 256, 0, stream>>>(rfill, rsumb, cnt, inv);
  k_packW<<<dim3(NT, NK), 64, 0, stream>>>(gcnW1, hwWr, Wp);
  int n4 = KG_E * E_DIM / 4;
  k_toh<<<(n4 + 255) / 256, 256, 0, stream>>>(primal, B0, n4);

  int rg = (KG_E + 3) / 4;

  k_rlayer<<<2 * KG_R, 192, 0, stream>>>(B0, lidx, lsv, cnt, inv, atten_r, wpk);
  k_att_csr<<<rg, 256, 0, stream>>>(B0, wpk, eer_start, eer_scol, eer_srel,
                                    B0, 0.1f, B1);
  k_rlayer<<<2 * KG_R, 192, 0, stream>>>(B1, lidx, lsv, cnt, inv, atten_r, wpk);
  k_att_csr<<<rg, 256, 0, stream>>>(B1, wpk, eer_start, eer_scol, eer_srel,
                                    B0, 0.3f, B2);

  dim3 gg((KG_E + 31) / 32, 5);
  k_gemm2_mfma<<<gg, 256, 0, stream>>>(B2, Wp, Fb, Gb, KG_E);
  k_spmm_hw<<<rg, 256, 0, stream>>>(Fb, adj_start, adj_scol, adj_sval,
                                    Gb, B2, hwbr, B1, (float*)nullptr);

  k_gemm2_mfma<<<gg, 256, 0, stream>>>(B1, Wp, Fb, Gb, KG_E);
  k_spmm_hw<<<rg, 256, 0, stream>>>(Fb, adj_start, adj_scol, adj_sval,
                                    Gb, B1, hwbr, (__half*)nullptr, out);
}